// Round 1
// baseline (208.146 us; speedup 1.0000x reference)
//
#include <hip/hip_runtime.h>
#include <stdint.h>
#include <stddef.h>

typedef __bf16 bf16;
typedef __bf16 bf16x8 __attribute__((ext_vector_type(8)));
typedef __bf16 bf16x4 __attribute__((ext_vector_type(4)));
typedef float f32x4 __attribute__((ext_vector_type(4)));

static_assert(sizeof(bf16x8) == 16, "bf16x8 must be 16B");

__device__ __forceinline__ void gload_lds16(const void* g, void* l) {
    __builtin_amdgcn_global_load_lds(
        (const __attribute__((address_space(1))) uint32_t*)g,
        (__attribute__((address_space(3))) uint32_t*)l, 16, 0, 0);
}

// ---------------------------------------------------------------------------
// Kernel 1: attention  (pool 56x56 -> 28x28, MLP 784->196->16, softmax/T)
// grid = 8 (one block per sample), block = 256
// ---------------------------------------------------------------------------
__global__ void attn_kernel(const float* __restrict__ sk,
                            const float* __restrict__ w1,
                            const float* __restrict__ w2,
                            float* __restrict__ att) {
    const int b = blockIdx.x, t = threadIdx.x;
    __shared__ float pooled[784];
    __shared__ float hdn[196];
    __shared__ float logits[16];
    const float* skb = sk + (size_t)b * 3136;
    for (int e = t; e < 784; e += 256) {
        int oy = e / 28, ox = e % 28;
        const float* p = skb + (oy * 2) * 56 + ox * 2;
        pooled[e] = 0.25f * (p[0] + p[1] + p[56] + p[57]);
    }
    __syncthreads();
    if (t < 196) {
        float s = 0.f;
        const float* wr = w1 + (size_t)t * 784;
        for (int i = 0; i < 784; ++i) s += pooled[i] * wr[i];
        hdn[t] = s > 0.f ? s : 0.f;
    }
    __syncthreads();
    if (t < 16) {
        float s = 0.f;
        const float* wr = w2 + (size_t)t * 196;
        for (int j = 0; j < 196; ++j) s += hdn[j] * wr[j];
        logits[t] = s * (1.0f / 30.0f);
    }
    __syncthreads();
    if (t == 0) {
        float m = logits[0];
        for (int k = 1; k < 16; ++k) m = fmaxf(m, logits[k]);
        float e16[16], sum = 0.f;
        for (int k = 0; k < 16; ++k) { e16[k] = expf(logits[k] - m); sum += e16[k]; }
        float inv = 1.f / sum;
        for (int k = 0; k < 16; ++k) att[b * 16 + k] = e16[k] * inv;
    }
}

// ---------------------------------------------------------------------------
// Kernel 2: weight aggregation + bias aggregation.
// grid = 1024 (chunk-major: co = bid&255, chunk = bid>>8), block = 256.
// agg_w2 layout: [b][pos][chunk(4)][half(2)][cg(8)][co_l(128)][c8(8)]  bf16
// ---------------------------------------------------------------------------
__global__ __launch_bounds__(256) void agg_kernel(
    const float* __restrict__ weight,
    const float* __restrict__ bias,
    const float* __restrict__ att,
    bf16* __restrict__ aggw,
    float* __restrict__ aggb) {
    const int bid = blockIdx.x;
    const int co = bid & 255, chunk = bid >> 8;
    const int t = threadIdx.x;

    __shared__ bf16 accW[8 * 576];  // [b][el]  (el = local e within chunk)

    if (chunk == 0 && t < 8) {
        float s = 0.f;
        for (int k = 0; k < 16; ++k) s += att[t * 16 + k] * bias[k * 256 + co];
        aggb[t * 256 + co] = s;
    }

    if (t < 144) {
        const float* wbase = weight + (size_t)co * 2304 + (size_t)chunk * 576 + (size_t)t * 4;
        float4 wv[16];
#pragma unroll
        for (int k = 0; k < 16; ++k)
            wv[k] = *(const float4*)(wbase + (size_t)k * 589824);
        float a[8][4];
#pragma unroll
        for (int b = 0; b < 8; ++b)
#pragma unroll
            for (int j = 0; j < 4; ++j) a[b][j] = 0.f;
#pragma unroll
        for (int k = 0; k < 16; ++k) {
#pragma unroll
            for (int b = 0; b < 8; ++b) {
                const float av = att[b * 16 + k];  // uniform -> scalar load
                a[b][0] += av * wv[k].x;
                a[b][1] += av * wv[k].y;
                a[b][2] += av * wv[k].z;
                a[b][3] += av * wv[k].w;
            }
        }
#pragma unroll
        for (int b = 0; b < 8; ++b) {
            bf16x4 v;
#pragma unroll
            for (int j = 0; j < 4; ++j) v[j] = (bf16)a[b][j];
            *(bf16x4*)&accW[b * 576 + t * 4] = v;
        }
    }
    __syncthreads();

    // write out in the conv-DMA-native layout
    const int half = co >> 7, co_l = co & 127;
    for (int s = t; s < 576; s += 256) {
        const int b = s / 72, r = s - b * 72;
        const int pos = r >> 3, cg = r & 7;
        bf16x8 v;
#pragma unroll
        for (int c = 0; c < 8; ++c) v[c] = accW[b * 576 + (cg * 8 + c) * 9 + pos];
        size_t o = (((((size_t)b * 9 + pos) * 4 + chunk) * 2 + half) * 8 + cg) * 128 + co_l;
        *(bf16x8*)(aggw + o * 8) = v;
    }
}

// ---------------------------------------------------------------------------
// Kernel 3: transpose x[b][ci][y][x] fp32 -> x_t2[b][y][cg(32)][x(64)][c8(8)] bf16
// grid = 512 (b*64+y), block = 256
// ---------------------------------------------------------------------------
__global__ void transpose_kernel(const float* __restrict__ x, bf16* __restrict__ xt) {
    const int bid = blockIdx.x;
    const int b = bid >> 6, y = bid & 63;
    const int t = threadIdx.x;
    __shared__ bf16 T[256 * 64];  // [ci][x]
    const float* src = x + (size_t)b * 256 * 4096 + (size_t)y * 64;
    for (int i = 0; i < 16; ++i) {
        int v = t + 256 * i;              // 4096 float4 chunks
        int ci = v >> 4, x4 = (v & 15) * 4;
        float4 f = *(const float4*)(src + (size_t)ci * 4096 + x4);
        bf16* d = &T[ci * 64 + x4];
        d[0] = (bf16)f.x; d[1] = (bf16)f.y; d[2] = (bf16)f.z; d[3] = (bf16)f.w;
    }
    __syncthreads();
    bf16* dstb = xt + (size_t)bid * 16384;
    for (int i = 0; i < 8; ++i) {
        int c2 = t + 256 * i;             // 2048 16B chunks: [cg][x]
        int cg = c2 >> 6, xx = c2 & 63;
        bf16x8 v;
#pragma unroll
        for (int c = 0; c < 8; ++c) v[c] = T[(cg * 8 + c) * 64 + xx];
        *(bf16x8*)(dstb + (size_t)c2 * 8) = v;
    }
}

// ---------------------------------------------------------------------------
// Kernel 4: implicit-GEMM conv + bias + residual.  (v2)
// grid = 512: bid = [b(8)][half(2)][ytile(32)], block = 256 (4 waves, 2x2).
// Block tile: 128 co x (2 rows x 64 cols). K-loop: 4 ci-chunks of 64, 9 taps.
//
// v2 changes vs v1:
//  - A-fragments (weights) loaded global->VGPR directly (coalesced 256B
//    segments, L1/L2-served; aggw slice shared by 32 blocks). No Ws LDS
//    array, no per-tap barriers (was 2 barriers x 36 taps with full vmcnt
//    drains = the 30% MfmaUtil stall).
//  - Freed LDS spent on double-buffered X tile: prefetch chunk c+1 via
//    global_load_lds while computing all 9 taps of chunk c (288 MFMAs/wave
//    between barriers). 6 barriers/block total (was 76).
// ---------------------------------------------------------------------------
__global__ __launch_bounds__(256, 2) void conv_kernel(
    const bf16* __restrict__ xt, const bf16* __restrict__ aggw,
    const float* __restrict__ aggb, const float* __restrict__ xin,
    float* __restrict__ out) {
    const int bid = blockIdx.x;
    const int ytile = bid & 31;
    const int half = (bid >> 5) & 1;
    const int b = bid >> 6;
    const int tid = threadIdx.x;
    const int wave = tid >> 6, lane = tid & 63;
    const int wm = wave & 1, wn = wave >> 1;
    const int lane15 = lane & 15, quad = lane >> 4;

    __shared__ __align__(16) bf16 Xs[2][4][8][66][8];  // [dbuf][row][cg][col(halo)][c8]

    f32x4 acc[4][4];
#pragma unroll
    for (int mt = 0; mt < 4; ++mt)
#pragma unroll
        for (int nt = 0; nt < 4; ++nt) acc[mt][nt] = f32x4{0.f, 0.f, 0.f, 0.f};

    // zero both X buffers once: halo cols 0/65 and out-of-image rows stay 0.
    {
        uint4 z; z.x = z.y = z.z = z.w = 0u;
        uint4* p = (uint4*)&Xs[0][0][0][0][0];
        for (int i = tid; i < 4224; i += 256) p[i] = z;
    }

    const int yrow = ytile * 2 - 1 + wave;          // wave w stages halo row w
    const bool rowok = (yrow >= 0) && (yrow < 64);
    const bf16* xsrc = xt + ((size_t)b * 64 + (rowok ? yrow : 0)) * 16384 + (size_t)lane * 8;

    // per-lane base into aggw (bf16 elements):
    // addr = (b*9+pos)*65536 + chunk*16384 + half*8192 + (s*4+quad)*1024
    //        + (wm*64 + mt*16 + lane15)*8
    const bf16* wlane = aggw + (size_t)b * 9 * 65536 + (size_t)half * 8192
                      + (size_t)quad * 1024 + (size_t)(wm * 64 + lane15) * 8;

    __syncthreads();                                // zero-fill visible to all
    if (rowok) {
        bf16* xdst = &Xs[0][wave][0][1][0];
#pragma unroll
        for (int cg = 0; cg < 8; ++cg)
            gload_lds16(xsrc + cg * 512, xdst + cg * 528);
    }
    __syncthreads();                                // chunk 0 staged (vmcnt drain)

    for (int chunk = 0; chunk < 4; ++chunk) {
        const int cur = chunk & 1;
        // prefetch next chunk's X rows into the other buffer (overlaps compute)
        if (chunk < 3 && rowok) {
            const bf16* s0 = xsrc + (size_t)(chunk + 1) * 4096;
            bf16* xdst = &Xs[cur ^ 1][wave][0][1][0];
#pragma unroll
            for (int cg = 0; cg < 8; ++cg)
                gload_lds16(s0 + cg * 512, xdst + cg * 528);
        }
        const bf16* wchunk = wlane + (size_t)chunk * 16384;
#pragma unroll
        for (int pos = 0; pos < 9; ++pos) {
            const int kh = pos / 3, kw = pos - kh * 3;
            const int xr = wn + kh;
            const bf16* wtap = wchunk + (size_t)pos * 65536;
            bf16x8 afr[2][4];
#pragma unroll
            for (int s = 0; s < 2; ++s)
#pragma unroll
                for (int mt = 0; mt < 4; ++mt)
                    afr[s][mt] = *(const bf16x8*)(wtap + s * 4096 + mt * 128);
#pragma unroll
            for (int s = 0; s < 2; ++s) {
                const int cg = s * 4 + quad;
                bf16x8 bfr[4];
#pragma unroll
                for (int nt = 0; nt < 4; ++nt)
                    bfr[nt] = *(const bf16x8*)&Xs[cur][xr][cg][kw + nt * 16 + lane15][0];
#pragma unroll
                for (int mt = 0; mt < 4; ++mt)
#pragma unroll
                    for (int nt = 0; nt < 4; ++nt)
                        acc[mt][nt] = __builtin_amdgcn_mfma_f32_16x16x32_bf16(
                            afr[s][mt], bfr[nt], acc[mt][nt], 0, 0, 0);
            }
        }
        __syncthreads();                            // prefetch landed; buffers swap
    }

    // epilogue: conv + agg_b + residual, fp32 out
    const int y = ytile * 2 + wn;
#pragma unroll
    for (int mt = 0; mt < 4; ++mt) {
#pragma unroll
        for (int r = 0; r < 4; ++r) {
            const int co = half * 128 + wm * 64 + mt * 16 + quad * 4 + r;
            const float bbv = aggb[b * 256 + co];
            const size_t rowbase = (((size_t)b * 256 + co) * 64 + y) * 64;
#pragma unroll
            for (int nt = 0; nt < 4; ++nt) {
                const size_t oidx = rowbase + nt * 16 + lane15;
                out[oidx] = acc[mt][nt][r] + bbv + xin[oidx];
            }
        }
    }
}

// ---------------------------------------------------------------------------
extern "C" void kernel_launch(void* const* d_in, const int* in_sizes, int n_in,
                              void* d_out, int out_size, void* d_ws, size_t ws_size,
                              hipStream_t stream) {
    const float* x    = (const float*)d_in[0];  // [8,256,64,64]
    const float* sk   = (const float*)d_in[1];  // [8,1,56,56]
    const float* wgt  = (const float*)d_in[2];  // [16,256,256,3,3]
    const float* bias = (const float*)d_in[3];  // [16,256]
    const float* w1   = (const float*)d_in[4];  // [196,784]
    const float* w2   = (const float*)d_in[5];  // [16,196]
    float* out = (float*)d_out;

    char* ws = (char*)d_ws;
    float* att  = (float*)(ws + 0);                      // 512 B
    float* aggb = (float*)(ws + 1024);                   // 8 KB
    bf16*  aggw = (bf16*)(ws + 16384);                   // 9,437,184 B
    bf16*  xt   = (bf16*)(ws + 16384 + 9437184);         // 16,777,216 B

    attn_kernel<<<8, 256, 0, stream>>>(sk, w1, w2, att);
    agg_kernel<<<1024, 256, 0, stream>>>(wgt, bias, att, aggw, aggb);
    transpose_kernel<<<512, 256, 0, stream>>>(x, xt);
    conv_kernel<<<512, 256, 0, stream>>>(xt, aggw, aggb, x, out);
}

// Round 2
// 199.098 us; speedup vs baseline: 1.0454x; 1.0454x over previous
//
#include <hip/hip_runtime.h>
#include <stdint.h>
#include <stddef.h>

typedef __bf16 bf16;
typedef __bf16 bf16x8 __attribute__((ext_vector_type(8)));
typedef __bf16 bf16x4 __attribute__((ext_vector_type(4)));
typedef float f32x4 __attribute__((ext_vector_type(4)));

static_assert(sizeof(bf16x8) == 16, "bf16x8 must be 16B");

__device__ __forceinline__ void gload_lds16(const void* g, void* l) {
    __builtin_amdgcn_global_load_lds(
        (const __attribute__((address_space(1))) uint32_t*)g,
        (__attribute__((address_space(3))) uint32_t*)l, 16, 0, 0);
}

// ---------------------------------------------------------------------------
// Kernel 1: attention  (pool 56x56 -> 28x28, MLP 784->196->16, softmax/T)
// grid = 8 (one block per sample), block = 256
// ---------------------------------------------------------------------------
__global__ void attn_kernel(const float* __restrict__ sk,
                            const float* __restrict__ w1,
                            const float* __restrict__ w2,
                            float* __restrict__ att) {
    const int b = blockIdx.x, t = threadIdx.x;
    __shared__ float pooled[784];
    __shared__ float hdn[196];
    __shared__ float logits[16];
    const float* skb = sk + (size_t)b * 3136;
    for (int e = t; e < 784; e += 256) {
        int oy = e / 28, ox = e % 28;
        const float* p = skb + (oy * 2) * 56 + ox * 2;
        pooled[e] = 0.25f * (p[0] + p[1] + p[56] + p[57]);
    }
    __syncthreads();
    if (t < 196) {
        float s = 0.f;
        const float* wr = w1 + (size_t)t * 784;
        for (int i = 0; i < 784; ++i) s += pooled[i] * wr[i];
        hdn[t] = s > 0.f ? s : 0.f;
    }
    __syncthreads();
    if (t < 16) {
        float s = 0.f;
        const float* wr = w2 + (size_t)t * 196;
        for (int j = 0; j < 196; ++j) s += hdn[j] * wr[j];
        logits[t] = s * (1.0f / 30.0f);
    }
    __syncthreads();
    if (t == 0) {
        float m = logits[0];
        for (int k = 1; k < 16; ++k) m = fmaxf(m, logits[k]);
        float e16[16], sum = 0.f;
        for (int k = 0; k < 16; ++k) { e16[k] = expf(logits[k] - m); sum += e16[k]; }
        float inv = 1.f / sum;
        for (int k = 0; k < 16; ++k) att[b * 16 + k] = e16[k] * inv;
    }
}

// ---------------------------------------------------------------------------
// Kernel 2: weight aggregation + bias aggregation.
// grid = 1024 (chunk-major: co = bid&255, chunk = bid>>8), block = 256.
// agg_w2 layout: [b][pos][chunk(4)][half(2)][cg(8)][co_l(128)][c8(8)]  bf16
// ---------------------------------------------------------------------------
__global__ __launch_bounds__(256) void agg_kernel(
    const float* __restrict__ weight,
    const float* __restrict__ bias,
    const float* __restrict__ att,
    bf16* __restrict__ aggw,
    float* __restrict__ aggb) {
    const int bid = blockIdx.x;
    const int co = bid & 255, chunk = bid >> 8;
    const int t = threadIdx.x;

    __shared__ bf16 accW[8 * 576];  // [b][el]  (el = local e within chunk)

    if (chunk == 0 && t < 8) {
        float s = 0.f;
        for (int k = 0; k < 16; ++k) s += att[t * 16 + k] * bias[k * 256 + co];
        aggb[t * 256 + co] = s;
    }

    if (t < 144) {
        const float* wbase = weight + (size_t)co * 2304 + (size_t)chunk * 576 + (size_t)t * 4;
        float4 wv[16];
#pragma unroll
        for (int k = 0; k < 16; ++k)
            wv[k] = *(const float4*)(wbase + (size_t)k * 589824);
        float a[8][4];
#pragma unroll
        for (int b = 0; b < 8; ++b)
#pragma unroll
            for (int j = 0; j < 4; ++j) a[b][j] = 0.f;
#pragma unroll
        for (int k = 0; k < 16; ++k) {
#pragma unroll
            for (int b = 0; b < 8; ++b) {
                const float av = att[b * 16 + k];  // uniform -> scalar load
                a[b][0] += av * wv[k].x;
                a[b][1] += av * wv[k].y;
                a[b][2] += av * wv[k].z;
                a[b][3] += av * wv[k].w;
            }
        }
#pragma unroll
        for (int b = 0; b < 8; ++b) {
            bf16x4 v;
#pragma unroll
            for (int j = 0; j < 4; ++j) v[j] = (bf16)a[b][j];
            *(bf16x4*)&accW[b * 576 + t * 4] = v;
        }
    }
    __syncthreads();

    // write out in the conv-DMA-native layout
    const int half = co >> 7, co_l = co & 127;
    for (int s = t; s < 576; s += 256) {
        const int b = s / 72, r = s - b * 72;
        const int pos = r >> 3, cg = r & 7;
        bf16x8 v;
#pragma unroll
        for (int c = 0; c < 8; ++c) v[c] = accW[b * 576 + (cg * 8 + c) * 9 + pos];
        size_t o = (((((size_t)b * 9 + pos) * 4 + chunk) * 2 + half) * 8 + cg) * 128 + co_l;
        *(bf16x8*)(aggw + o * 8) = v;
    }
}

// ---------------------------------------------------------------------------
// Kernel 3: transpose x[b][ci][y][x] fp32 -> x_t2[b][y][cg(32)][x(64)][c8(8)] bf16
// grid = 512 (b*64+y), block = 256
// ---------------------------------------------------------------------------
__global__ void transpose_kernel(const float* __restrict__ x, bf16* __restrict__ xt) {
    const int bid = blockIdx.x;
    const int b = bid >> 6, y = bid & 63;
    const int t = threadIdx.x;
    __shared__ bf16 T[256 * 64];  // [ci][x]
    const float* src = x + (size_t)b * 256 * 4096 + (size_t)y * 64;
    for (int i = 0; i < 16; ++i) {
        int v = t + 256 * i;              // 4096 float4 chunks
        int ci = v >> 4, x4 = (v & 15) * 4;
        float4 f = *(const float4*)(src + (size_t)ci * 4096 + x4);
        bf16* d = &T[ci * 64 + x4];
        d[0] = (bf16)f.x; d[1] = (bf16)f.y; d[2] = (bf16)f.z; d[3] = (bf16)f.w;
    }
    __syncthreads();
    bf16* dstb = xt + (size_t)bid * 16384;
    for (int i = 0; i < 8; ++i) {
        int c2 = t + 256 * i;             // 2048 16B chunks: [cg][x]
        int cg = c2 >> 6, xx = c2 & 63;
        bf16x8 v;
#pragma unroll
        for (int c = 0; c < 8; ++c) v[c] = T[(cg * 8 + c) * 64 + xx];
        *(bf16x8*)(dstb + (size_t)c2 * 8) = v;
    }
}

// ---------------------------------------------------------------------------
// Kernel 4: implicit-GEMM conv + bias + residual.  (v3)
// grid = 512: bid = [b(8)][half(2)][ytile(32)], block = 256 (4 waves, 2x2).
// Block tile: 128 co x (2 rows x 64 cols). K-loop: 4 ci-chunks of 64, 9 taps.
//
// v3 (post-mortem of v2): weights back in LDS (v1 path, 50us) but DOUBLE-
// BUFFERED: at tap p issue the DMA for tap p+1 into the idle buffer, compute
// tap p's 32 MFMAs (~310 SIMD-cyc at 2 blocks/CU -- covers L2 latency), then
// raw s_barrier with explicit vmcnt(0) (only this tap's 4 stage ops are
// outstanding -- no cross-draining, unlike v2 where in-order vmcnt forced the
// X prefetch to drain at every tap). X is single-buffered; its stage latency
// is exposed only 3x/block at chunk boundaries. LDS 66.5KB -> 2 blocks/CU.
// ---------------------------------------------------------------------------
__global__ __launch_bounds__(256, 2) void conv_kernel(
    const bf16* __restrict__ xt, const bf16* __restrict__ aggw,
    const float* __restrict__ aggb, const float* __restrict__ xin,
    float* __restrict__ out) {
    const int bid = blockIdx.x;
    const int ytile = bid & 31;
    const int half = (bid >> 5) & 1;
    const int b = bid >> 6;
    const int tid = threadIdx.x;
    const int wave = tid >> 6, lane = tid & 63;
    const int wm = wave & 1, wn = wave >> 1;
    const int lane15 = lane & 15, quad = lane >> 4;

    __shared__ __align__(16) bf16 Xs[4][8][66][8];   // [row][cg][col(halo)][c8]  33.8 KB
    __shared__ __align__(16) bf16 Ws[2][8][128][8];  // [dbuf][cg][co_l][c8]      32 KB

    f32x4 acc[4][4];
#pragma unroll
    for (int mt = 0; mt < 4; ++mt)
#pragma unroll
        for (int nt = 0; nt < 4; ++nt) acc[mt][nt] = f32x4{0.f, 0.f, 0.f, 0.f};

    // zero X tile once: halo cols 0/65 and out-of-image rows stay 0.
    {
        uint4 z; z.x = z.y = z.z = z.w = 0u;
        uint4* p = (uint4*)&Xs[0][0][0][0];
        for (int i = tid; i < 2112; i += 256) p[i] = z;
    }
    __syncthreads();  // zero-fill done before any DMA lands

    const int yrow = ytile * 2 - 1 + wave;          // wave w stages halo row w
    const bool rowok = (yrow >= 0) && (yrow < 64);
    const bf16* xsrc = xt + ((size_t)b * 64 + (rowok ? yrow : 0)) * 16384 + (size_t)lane * 8;
    bf16* xdstbase = &Xs[wave][0][1][0];            // +cg*528 per cg

    // per-wave weight staging: wave w stages 4KB slice (4 x 64 lanes x 16B)
    // src element offset: b*589824 + pos*65536 + chunk*16384 + half*8192
    //                     + wave*2048 + i*512 + lane*8
    const bf16* wsrcbase = aggw + (size_t)b * 589824 + (size_t)half * 8192
                         + (size_t)wave * 2048 + (size_t)lane * 8;
    bf16* wslice0 = ((bf16*)&Ws[0][0][0][0]) + wave * 2048;
    bf16* wslice1 = ((bf16*)&Ws[1][0][0][0]) + wave * 2048;

    // prologue: stage X chunk0 + Ws(chunk0,pos0) -> buf0
    if (rowok) {
#pragma unroll
        for (int cg = 0; cg < 8; ++cg)
            gload_lds16(xsrc + cg * 512, xdstbase + cg * 528);
    }
#pragma unroll
    for (int i = 0; i < 4; ++i)
        gload_lds16(wsrcbase + i * 512, wslice0 + i * 512);
    asm volatile("s_waitcnt vmcnt(0)" ::: "memory");
    __builtin_amdgcn_s_barrier();

    for (int chunk = 0; chunk < 4; ++chunk) {
#pragma unroll
        for (int pos = 0; pos < 9; ++pos) {
            const int bufp = (chunk + pos) & 1;       // == (chunk*9+pos)&1
            // ---- issue next tap's weight stage into the idle buffer ----
            bf16* wnext = bufp ? wslice0 : wslice1;
            if (pos < 8) {
                const bf16* s0 = wsrcbase + (size_t)(pos + 1) * 65536 + (size_t)chunk * 16384;
#pragma unroll
                for (int i = 0; i < 4; ++i)
                    gload_lds16(s0 + i * 512, wnext + i * 512);
            } else if (chunk < 3) {
                const bf16* s0 = wsrcbase + (size_t)(chunk + 1) * 16384;  // pos0 of next chunk
#pragma unroll
                for (int i = 0; i < 4; ++i)
                    gload_lds16(s0 + i * 512, wnext + i * 512);
            }
            // ---- compute tap p from Ws[bufp] (DMA overlaps these MFMAs) ----
            const int kh = pos / 3, kw = pos - kh * 3;
            const int xr = wn + kh;
            const bf16* wcur = (const bf16*)&Ws[bufp][0][0][0];
#pragma unroll
            for (int s = 0; s < 2; ++s) {
                const int cg = s * 4 + quad;
                bf16x8 afr[4], bfr[4];
#pragma unroll
                for (int mt = 0; mt < 4; ++mt)
                    afr[mt] = *(const bf16x8*)(wcur + (size_t)cg * 1024
                                               + (size_t)(wm * 64 + mt * 16 + lane15) * 8);
#pragma unroll
                for (int nt = 0; nt < 4; ++nt)
                    bfr[nt] = *(const bf16x8*)&Xs[xr][cg][kw + nt * 16 + lane15][0];
#pragma unroll
                for (int mt = 0; mt < 4; ++mt)
#pragma unroll
                    for (int nt = 0; nt < 4; ++nt)
                        acc[mt][nt] = __builtin_amdgcn_mfma_f32_16x16x32_bf16(
                            afr[mt], bfr[nt], acc[mt][nt], 0, 0, 0);
            }
            // ---- tap-end sync: wait only this tap's 4 stage ops, then barrier
            if (chunk < 3 || pos < 8) {
                asm volatile("s_waitcnt vmcnt(0) lgkmcnt(0)" ::: "memory");
                __builtin_amdgcn_s_barrier();
            }
        }
        // ---- chunk boundary: restage X (single buffer; reads all done) ----
        if (chunk < 3) {
            if (rowok) {
                const bf16* s0 = xsrc + (size_t)(chunk + 1) * 4096;
#pragma unroll
                for (int cg = 0; cg < 8; ++cg)
                    gload_lds16(s0 + cg * 512, xdstbase + cg * 528);
            }
            asm volatile("s_waitcnt vmcnt(0)" ::: "memory");
            __builtin_amdgcn_s_barrier();
        }
    }

    // epilogue: conv + agg_b + residual, fp32 out
    const int y = ytile * 2 + wn;
#pragma unroll
    for (int mt = 0; mt < 4; ++mt) {
#pragma unroll
        for (int r = 0; r < 4; ++r) {
            const int co = half * 128 + wm * 64 + mt * 16 + quad * 4 + r;
            const float bbv = aggb[b * 256 + co];
            const size_t rowbase = (((size_t)b * 256 + co) * 64 + y) * 64;
#pragma unroll
            for (int nt = 0; nt < 4; ++nt) {
                const size_t oidx = rowbase + nt * 16 + lane15;
                out[oidx] = acc[mt][nt][r] + bbv + xin[oidx];
            }
        }
    }
}

// ---------------------------------------------------------------------------
extern "C" void kernel_launch(void* const* d_in, const int* in_sizes, int n_in,
                              void* d_out, int out_size, void* d_ws, size_t ws_size,
                              hipStream_t stream) {
    const float* x    = (const float*)d_in[0];  // [8,256,64,64]
    const float* sk   = (const float*)d_in[1];  // [8,1,56,56]
    const float* wgt  = (const float*)d_in[2];  // [16,256,256,3,3]
    const float* bias = (const float*)d_in[3];  // [16,256]
    const float* w1   = (const float*)d_in[4];  // [196,784]
    const float* w2   = (const float*)d_in[5];  // [16,196]
    float* out = (float*)d_out;

    char* ws = (char*)d_ws;
    float* att  = (float*)(ws + 0);                      // 512 B
    float* aggb = (float*)(ws + 1024);                   // 8 KB
    bf16*  aggw = (bf16*)(ws + 16384);                   // 9,437,184 B
    bf16*  xt   = (bf16*)(ws + 16384 + 9437184);         // 16,777,216 B

    attn_kernel<<<8, 256, 0, stream>>>(sk, w1, w2, att);
    agg_kernel<<<1024, 256, 0, stream>>>(wgt, bias, att, aggw, aggb);
    transpose_kernel<<<512, 256, 0, stream>>>(x, xt);
    conv_kernel<<<512, 256, 0, stream>>>(xt, aggw, aggb, x, out);
}

// Round 3
// 198.294 us; speedup vs baseline: 1.0497x; 1.0041x over previous
//
#include <hip/hip_runtime.h>
#include <stdint.h>
#include <stddef.h>

typedef __bf16 bf16;
typedef __bf16 bf16x8 __attribute__((ext_vector_type(8)));
typedef __bf16 bf16x4 __attribute__((ext_vector_type(4)));
typedef float f32x4 __attribute__((ext_vector_type(4)));

static_assert(sizeof(bf16x8) == 16, "bf16x8 must be 16B");

__device__ __forceinline__ void gload_lds16(const void* g, void* l) {
    __builtin_amdgcn_global_load_lds(
        (const __attribute__((address_space(1))) uint32_t*)g,
        (__attribute__((address_space(3))) uint32_t*)l, 16, 0, 0);
}

// ---------------------------------------------------------------------------
// Kernel 1: attention  (pool 56x56 -> 28x28, MLP 784->196->16, softmax/T)
// grid = 8, block = 1024.  v2: coalesced w1 GEMV — 16 lanes per output row
// read 64B-contiguous segments + shfl reduce (old version: lane t read row t
// scalar = fully uncoalesced, latency-bound).
// ---------------------------------------------------------------------------
__global__ __launch_bounds__(1024) void attn_kernel(const float* __restrict__ sk,
                                                    const float* __restrict__ w1,
                                                    const float* __restrict__ w2,
                                                    float* __restrict__ att) {
    const int b = blockIdx.x, t = threadIdx.x;
    __shared__ float pooled[784];
    __shared__ float hdn[196];
    __shared__ float logits[16];
    const float* skb = sk + (size_t)b * 3136;
    if (t < 784) {
        int oy = t / 28, ox = t % 28;
        const float* p = skb + (oy * 2) * 56 + ox * 2;
        pooled[t] = 0.25f * (p[0] + p[1] + p[56] + p[57]);
    }
    __syncthreads();
    const int q = t & 15, jg = t >> 4;  // 64 groups of 16 lanes
#pragma unroll
    for (int rep = 0; rep < 4; ++rep) {
        const int j = rep * 64 + jg;
        float s = 0.f;
        if (j < 196) {
            const float* wr = w1 + (size_t)j * 784 + q;
#pragma unroll 7
            for (int i = 0; i < 49; ++i) s += pooled[q + i * 16] * wr[i * 16];
        }
#pragma unroll
        for (int off = 8; off; off >>= 1) s += __shfl_xor(s, off, 16);
        if (j < 196 && q == 0) hdn[j] = s > 0.f ? s : 0.f;
    }
    __syncthreads();
    if (t < 256) {
        const int jj = t >> 4, qq = t & 15;
        float s = 0.f;
#pragma unroll
        for (int i = 0; i < 13; ++i) {
            const int idx = qq + i * 16;
            if (idx < 196) s += hdn[idx] * w2[jj * 196 + idx];
        }
#pragma unroll
        for (int off = 8; off; off >>= 1) s += __shfl_xor(s, off, 16);
        if (qq == 0) logits[jj] = s * (1.0f / 30.0f);
    }
    __syncthreads();
    if (t == 0) {
        float m = logits[0];
        for (int k = 1; k < 16; ++k) m = fmaxf(m, logits[k]);
        float e16[16], sum = 0.f;
        for (int k = 0; k < 16; ++k) { e16[k] = expf(logits[k] - m); sum += e16[k]; }
        float inv = 1.f / sum;
        for (int k = 0; k < 16; ++k) att[b * 16 + k] = e16[k] * inv;
    }
}

// ---------------------------------------------------------------------------
// Kernel 2: weight aggregation + bias aggregation.
// grid = 1024 (chunk-major: co = bid&255, chunk = bid>>8), block = 256.
// agg_w2 layout: [b][pos][chunk(4)][half(2)][cg(8)][co_l(128)][c8(8)]  bf16
// ---------------------------------------------------------------------------
__global__ __launch_bounds__(256) void agg_kernel(
    const float* __restrict__ weight,
    const float* __restrict__ bias,
    const float* __restrict__ att,
    bf16* __restrict__ aggw,
    float* __restrict__ aggb) {
    const int bid = blockIdx.x;
    const int co = bid & 255, chunk = bid >> 8;
    const int t = threadIdx.x;

    __shared__ bf16 accW[8 * 576];  // [b][el]  (el = local e within chunk)

    if (chunk == 0 && t < 8) {
        float s = 0.f;
        for (int k = 0; k < 16; ++k) s += att[t * 16 + k] * bias[k * 256 + co];
        aggb[t * 256 + co] = s;
    }

    if (t < 144) {
        const float* wbase = weight + (size_t)co * 2304 + (size_t)chunk * 576 + (size_t)t * 4;
        float4 wv[16];
#pragma unroll
        for (int k = 0; k < 16; ++k)
            wv[k] = *(const float4*)(wbase + (size_t)k * 589824);
        float a[8][4];
#pragma unroll
        for (int b = 0; b < 8; ++b)
#pragma unroll
            for (int j = 0; j < 4; ++j) a[b][j] = 0.f;
#pragma unroll
        for (int k = 0; k < 16; ++k) {
#pragma unroll
            for (int b = 0; b < 8; ++b) {
                const float av = att[b * 16 + k];  // uniform -> scalar load
                a[b][0] += av * wv[k].x;
                a[b][1] += av * wv[k].y;
                a[b][2] += av * wv[k].z;
                a[b][3] += av * wv[k].w;
            }
        }
#pragma unroll
        for (int b = 0; b < 8; ++b) {
            bf16x4 v;
#pragma unroll
            for (int j = 0; j < 4; ++j) v[j] = (bf16)a[b][j];
            *(bf16x4*)&accW[b * 576 + t * 4] = v;
        }
    }
    __syncthreads();

    // write out in the conv-DMA-native layout
    const int half = co >> 7, co_l = co & 127;
    for (int s = t; s < 576; s += 256) {
        const int b = s / 72, r = s - b * 72;
        const int pos = r >> 3, cg = r & 7;
        bf16x8 v;
#pragma unroll
        for (int c = 0; c < 8; ++c) v[c] = accW[b * 576 + (cg * 8 + c) * 9 + pos];
        size_t o = (((((size_t)b * 9 + pos) * 4 + chunk) * 2 + half) * 8 + cg) * 128 + co_l;
        *(bf16x8*)(aggw + o * 8) = v;
    }
}

// ---------------------------------------------------------------------------
// Kernel 3: transpose x[b][ci][y][x] fp32 -> x_t2[b][y][cg(32)][x(64)][c8(8)] bf16
// grid = 512 (b*64+y), block = 256
// ---------------------------------------------------------------------------
__global__ void transpose_kernel(const float* __restrict__ x, bf16* __restrict__ xt) {
    const int bid = blockIdx.x;
    const int b = bid >> 6, y = bid & 63;
    const int t = threadIdx.x;
    __shared__ bf16 T[256 * 64];  // [ci][x]
    const float* src = x + (size_t)b * 256 * 4096 + (size_t)y * 64;
    for (int i = 0; i < 16; ++i) {
        int v = t + 256 * i;              // 4096 float4 chunks
        int ci = v >> 4, x4 = (v & 15) * 4;
        float4 f = *(const float4*)(src + (size_t)ci * 4096 + x4);
        bf16* d = &T[ci * 64 + x4];
        d[0] = (bf16)f.x; d[1] = (bf16)f.y; d[2] = (bf16)f.z; d[3] = (bf16)f.w;
    }
    __syncthreads();
    bf16* dstb = xt + (size_t)bid * 16384;
    for (int i = 0; i < 8; ++i) {
        int c2 = t + 256 * i;             // 2048 16B chunks: [cg][x]
        int cg = c2 >> 6, xx = c2 & 63;
        bf16x8 v;
#pragma unroll
        for (int c = 0; c < 8; ++c) v[c] = T[(cg * 8 + c) * 64 + xx];
        *(bf16x8*)(dstb + (size_t)c2 * 8) = v;
    }
}

// ---------------------------------------------------------------------------
// Kernel 4: implicit-GEMM conv + bias + residual.  (v4)
// grid = 512: bid = ytile*16 + slice, slice = b*2+half  ->  bid%8 == slice%8
// so all 32 blocks sharing one 590KB aggw slice land on one XCD's L2.
// block = 256 (4 waves, 2x2). Tile: 128 co x (2 rows x 64 cols), 4 ci-chunks.
//
// v4 (post-mortem of v3): W-LDS path removed entirely.
//  - afr: global->VGPR, 1-tap register double-buffer (afr[2][..], all
//    compile-time indices). 16-lane-contiguous 256B segments, L1/L2-served.
//    Kills the 2.36M 4-way afr bank conflicts AND all per-tap barriers.
//  - X stays in LDS (bfr reads are 2-way = free), restaged 3x/kernel.
//    Barriers: 39 -> 8. LDS traffic/tap: ~1792 -> ~800 cyc < MFMA 1241.
// ---------------------------------------------------------------------------
__global__ __launch_bounds__(256, 2) void conv_kernel(
    const bf16* __restrict__ xt, const bf16* __restrict__ aggw,
    const float* __restrict__ aggb, const float* __restrict__ xin,
    float* __restrict__ out) {
    const int bid = blockIdx.x;
    const int slice = bid & 15, ytile = bid >> 4;   // XCD-locality swizzle
    const int b = slice >> 1, half = slice & 1;
    const int tid = threadIdx.x;
    const int wave = tid >> 6, lane = tid & 63;
    const int wm = wave & 1, wn = wave >> 1;
    const int lane15 = lane & 15, quad = lane >> 4;

    __shared__ __align__(16) bf16 Xs[4][8][66][8];   // [row][cg][col(halo)][c8]  33.8 KB

    f32x4 acc[4][4];
#pragma unroll
    for (int mt = 0; mt < 4; ++mt)
#pragma unroll
        for (int nt = 0; nt < 4; ++nt) acc[mt][nt] = f32x4{0.f, 0.f, 0.f, 0.f};

    // zero X tile once: halo cols 0/65 and out-of-image rows stay 0.
    {
        uint4 z; z.x = z.y = z.z = z.w = 0u;
        uint4* p = (uint4*)&Xs[0][0][0][0];
        for (int i = tid; i < 2112; i += 256) p[i] = z;
    }
    __syncthreads();  // zero-fill drained before any DMA can land

    const int yrow = ytile * 2 - 1 + wave;          // wave w stages halo row w
    const bool rowok = (yrow >= 0) && (yrow < 64);
    const bf16* xsrc = xt + ((size_t)b * 64 + (rowok ? yrow : 0)) * 16384 + (size_t)lane * 8;
    bf16* xdstbase = &Xs[wave][0][1][0];            // +cg*528 per cg

    // per-lane afr base (bf16 elements):
    // elem = b*589824 + pos*65536 + chunk*16384 + half*8192
    //        + (s*4+quad)*1024 + (wm*64 + mt*16 + lane15)*8
    const bf16* wlane = aggw + (size_t)b * 589824 + (size_t)half * 8192
                      + (size_t)quad * 1024 + (size_t)(wm * 64 + lane15) * 8;

    bf16x8 afr[2][2][4];  // [parity][s][mt] — all indices compile-time

    // prologue: stage X chunk0 + load afr(tap0)
    if (rowok) {
#pragma unroll
        for (int cg = 0; cg < 8; ++cg)
            gload_lds16(xsrc + cg * 512, xdstbase + cg * 528);
    }
#pragma unroll
    for (int s_ = 0; s_ < 2; ++s_)
#pragma unroll
        for (int mt = 0; mt < 4; ++mt)
            afr[0][s_][mt] = *(const bf16x8*)(wlane + s_ * 4096 + mt * 128);
    asm volatile("s_waitcnt vmcnt(0)" ::: "memory");
    __builtin_amdgcn_s_barrier();

    for (int cp = 0; cp < 2; ++cp) {                // chunk pairs (keeps parity static)
#pragma unroll
        for (int t = 0; t < 18; ++t) {
            const int par = t & 1;
            const int pos = t % 9;
            const int chunk = cp * 2 + t / 9;
            // ---- prefetch afr for next tap (register double-buffer) ----
            if (t < 17) {
                const int npos = (t + 1) % 9;
                const int nchunk = cp * 2 + (t + 1) / 9;
                const bf16* pb = wlane + (size_t)npos * 65536 + (size_t)nchunk * 16384;
#pragma unroll
                for (int s_ = 0; s_ < 2; ++s_)
#pragma unroll
                    for (int mt = 0; mt < 4; ++mt)
                        afr[par ^ 1][s_][mt] = *(const bf16x8*)(pb + s_ * 4096 + mt * 128);
            } else if (cp == 0) {                   // tap17 -> tap18 = chunk2, pos0
                const bf16* pb = wlane + (size_t)(cp * 2 + 2) * 16384;
#pragma unroll
                for (int s_ = 0; s_ < 2; ++s_)
#pragma unroll
                    for (int mt = 0; mt < 4; ++mt)
                        afr[par ^ 1][s_][mt] = *(const bf16x8*)(pb + s_ * 4096 + mt * 128);
            }
            // ---- compute tap (no barriers inside a chunk) ----
            const int kh = pos / 3, kw = pos - kh * 3;
            const int xr = wn + kh;
#pragma unroll
            for (int s_ = 0; s_ < 2; ++s_) {
                const int cg = s_ * 4 + quad;
                bf16x8 bfr[4];
#pragma unroll
                for (int nt = 0; nt < 4; ++nt)
                    bfr[nt] = *(const bf16x8*)&Xs[xr][cg][kw + nt * 16 + lane15][0];
#pragma unroll
                for (int mt = 0; mt < 4; ++mt)
#pragma unroll
                    for (int nt = 0; nt < 4; ++nt)
                        acc[mt][nt] = __builtin_amdgcn_mfma_f32_16x16x32_bf16(
                            afr[par][s_][mt], bfr[nt], acc[mt][nt], 0, 0, 0);
            }
            // ---- chunk boundary: restage X (3x per kernel) ----
            if (pos == 8 && (t == 8 || cp == 0)) {
                asm volatile("s_waitcnt lgkmcnt(0)" ::: "memory");
                __builtin_amdgcn_s_barrier();       // all bfr reads of this chunk done
                if (rowok) {
                    const bf16* s0 = xsrc + (size_t)(chunk + 1) * 4096;
#pragma unroll
                    for (int cg = 0; cg < 8; ++cg)
                        gload_lds16(s0 + cg * 512, xdstbase + cg * 528);
                }
                asm volatile("s_waitcnt vmcnt(0)" ::: "memory");
                __builtin_amdgcn_s_barrier();       // next chunk staged
            }
        }
    }

    // epilogue: conv + agg_b + residual, fp32 out
    const int y = ytile * 2 + wn;
#pragma unroll
    for (int mt = 0; mt < 4; ++mt) {
#pragma unroll
        for (int r = 0; r < 4; ++r) {
            const int co = half * 128 + wm * 64 + mt * 16 + quad * 4 + r;
            const float bbv = aggb[b * 256 + co];
            const size_t rowbase = (((size_t)b * 256 + co) * 64 + y) * 64;
#pragma unroll
            for (int nt = 0; nt < 4; ++nt) {
                const size_t oidx = rowbase + nt * 16 + lane15;
                out[oidx] = acc[mt][nt][r] + bbv + xin[oidx];
            }
        }
    }
}

// ---------------------------------------------------------------------------
extern "C" void kernel_launch(void* const* d_in, const int* in_sizes, int n_in,
                              void* d_out, int out_size, void* d_ws, size_t ws_size,
                              hipStream_t stream) {
    const float* x    = (const float*)d_in[0];  // [8,256,64,64]
    const float* sk   = (const float*)d_in[1];  // [8,1,56,56]
    const float* wgt  = (const float*)d_in[2];  // [16,256,256,3,3]
    const float* bias = (const float*)d_in[3];  // [16,256]
    const float* w1   = (const float*)d_in[4];  // [196,784]
    const float* w2   = (const float*)d_in[5];  // [16,196]
    float* out = (float*)d_out;

    char* ws = (char*)d_ws;
    float* att  = (float*)(ws + 0);                      // 512 B
    float* aggb = (float*)(ws + 1024);                   // 8 KB
    bf16*  aggw = (bf16*)(ws + 16384);                   // 9,437,184 B
    bf16*  xt   = (bf16*)(ws + 16384 + 9437184);         // 16,777,216 B

    attn_kernel<<<8, 1024, 0, stream>>>(sk, w1, w2, att);
    agg_kernel<<<1024, 256, 0, stream>>>(wgt, bias, att, aggw, aggb);
    transpose_kernel<<<512, 256, 0, stream>>>(x, xt);
    conv_kernel<<<512, 256, 0, stream>>>(xt, aggw, aggb, x, out);
}

// Round 5
// 190.718 us; speedup vs baseline: 1.0914x; 1.0397x over previous
//
#include <hip/hip_runtime.h>
#include <stdint.h>
#include <stddef.h>

typedef __bf16 bf16;
typedef __bf16 bf16x8 __attribute__((ext_vector_type(8)));
typedef __bf16 bf16x4 __attribute__((ext_vector_type(4)));
typedef float f32x4 __attribute__((ext_vector_type(4)));

static_assert(sizeof(bf16x8) == 16, "bf16x8 must be 16B");

__device__ __forceinline__ void gload_lds16(const void* g, void* l) {
    __builtin_amdgcn_global_load_lds(
        (const __attribute__((address_space(1))) uint32_t*)g,
        (__attribute__((address_space(3))) uint32_t*)l, 16, 0, 0);
}

// ---------------------------------------------------------------------------
// Kernel 1: attention  (pool 56x56 -> 28x28, MLP 784->196->16, softmax/T)
// grid = 8, block = 1024.  Coalesced w1 GEMV: 16 lanes per output row.
// ---------------------------------------------------------------------------
__global__ __launch_bounds__(1024) void attn_kernel(const float* __restrict__ sk,
                                                    const float* __restrict__ w1,
                                                    const float* __restrict__ w2,
                                                    float* __restrict__ att) {
    const int b = blockIdx.x, t = threadIdx.x;
    __shared__ float pooled[784];
    __shared__ float hdn[196];
    __shared__ float logits[16];
    const float* skb = sk + (size_t)b * 3136;
    if (t < 784) {
        int oy = t / 28, ox = t % 28;
        const float* p = skb + (oy * 2) * 56 + ox * 2;
        pooled[t] = 0.25f * (p[0] + p[1] + p[56] + p[57]);
    }
    __syncthreads();
    const int q = t & 15, jg = t >> 4;  // 64 groups of 16 lanes
#pragma unroll
    for (int rep = 0; rep < 4; ++rep) {
        const int j = rep * 64 + jg;
        float s = 0.f;
        if (j < 196) {
            const float* wr = w1 + (size_t)j * 784 + q;
#pragma unroll 7
            for (int i = 0; i < 49; ++i) s += pooled[q + i * 16] * wr[i * 16];
        }
#pragma unroll
        for (int off = 8; off; off >>= 1) s += __shfl_xor(s, off, 16);
        if (j < 196 && q == 0) hdn[j] = s > 0.f ? s : 0.f;
    }
    __syncthreads();
    if (t < 256) {
        const int jj = t >> 4, qq = t & 15;
        float s = 0.f;
#pragma unroll
        for (int i = 0; i < 13; ++i) {
            const int idx = qq + i * 16;
            if (idx < 196) s += hdn[idx] * w2[jj * 196 + idx];
        }
#pragma unroll
        for (int off = 8; off; off >>= 1) s += __shfl_xor(s, off, 16);
        if (qq == 0) logits[jj] = s * (1.0f / 30.0f);
    }
    __syncthreads();
    if (t == 0) {
        float m = logits[0];
        for (int k = 1; k < 16; ++k) m = fmaxf(m, logits[k]);
        float e16[16], sum = 0.f;
        for (int k = 0; k < 16; ++k) { e16[k] = expf(logits[k] - m); sum += e16[k]; }
        float inv = 1.f / sum;
        for (int k = 0; k < 16; ++k) att[b * 16 + k] = e16[k] * inv;
    }
}

// ---------------------------------------------------------------------------
// Kernel 2 (fused): weight aggregation (blocks 0..1023) + x transpose
// (blocks 1024..1535). Independent work; fusing removes one launch gap and
// overlaps agg's latency phase with transpose's BW phase.
// agg_w2 layout: [b][pos][chunk(4)][half(2)][cg(8)][co_l(128)][c8(8)]  bf16
// xt layout:     [b*64+y][cg(32)][x(64)][c8(8)]                        bf16
// ---------------------------------------------------------------------------
__global__ __launch_bounds__(256) void aggt_kernel(
    const float* __restrict__ weight,
    const float* __restrict__ bias,
    const float* __restrict__ att,
    bf16* __restrict__ aggw,
    float* __restrict__ aggb,
    const float* __restrict__ x,
    bf16* __restrict__ xt) {
    __shared__ __align__(16) char smem[32768];
    const int t = threadIdx.x;

    if (blockIdx.x >= 1024) {
        // ---- transpose block: x[b][ci][y][x] fp32 -> xt bf16 ----
        const int bid = blockIdx.x - 1024;
        const int b = bid >> 6, y = bid & 63;
        bf16* T = (bf16*)smem;  // [ci(256)][x(64)]
        const float* src = x + (size_t)b * 256 * 4096 + (size_t)y * 64;
        for (int i = 0; i < 16; ++i) {
            int v = t + 256 * i;              // 4096 float4 chunks
            int ci = v >> 4, x4 = (v & 15) * 4;
            float4 f = *(const float4*)(src + (size_t)ci * 4096 + x4);
            bf16* d = &T[ci * 64 + x4];
            d[0] = (bf16)f.x; d[1] = (bf16)f.y; d[2] = (bf16)f.z; d[3] = (bf16)f.w;
        }
        __syncthreads();
        bf16* dstb = xt + (size_t)bid * 16384;
        for (int i = 0; i < 8; ++i) {
            int c2 = t + 256 * i;             // 2048 16B chunks: [cg][x]
            int cg = c2 >> 6, xx = c2 & 63;
            bf16x8 v;
#pragma unroll
            for (int c = 0; c < 8; ++c) v[c] = T[(cg * 8 + c) * 64 + xx];
            *(bf16x8*)(dstb + (size_t)c2 * 8) = v;
        }
        return;
    }

    // ---- agg block ----
    const int bid = blockIdx.x;
    const int co = bid & 255, chunk = bid >> 8;
    bf16* accW = (bf16*)smem;  // [b][el]  8*576

    if (chunk == 0 && t < 8) {
        float s = 0.f;
        for (int k = 0; k < 16; ++k) s += att[t * 16 + k] * bias[k * 256 + co];
        aggb[t * 256 + co] = s;
    }

    if (t < 144) {
        const float* wbase = weight + (size_t)co * 2304 + (size_t)chunk * 576 + (size_t)t * 4;
        float4 wv[16];
#pragma unroll
        for (int k = 0; k < 16; ++k)
            wv[k] = *(const float4*)(wbase + (size_t)k * 589824);
        float a[8][4];
#pragma unroll
        for (int b = 0; b < 8; ++b)
#pragma unroll
            for (int j = 0; j < 4; ++j) a[b][j] = 0.f;
#pragma unroll
        for (int k = 0; k < 16; ++k) {
#pragma unroll
            for (int b = 0; b < 8; ++b) {
                const float av = att[b * 16 + k];  // uniform -> scalar load
                a[b][0] += av * wv[k].x;
                a[b][1] += av * wv[k].y;
                a[b][2] += av * wv[k].z;
                a[b][3] += av * wv[k].w;
            }
        }
#pragma unroll
        for (int b = 0; b < 8; ++b) {
            bf16x4 v;
#pragma unroll
            for (int j = 0; j < 4; ++j) v[j] = (bf16)a[b][j];
            *(bf16x4*)&accW[b * 576 + t * 4] = v;
        }
    }
    __syncthreads();

    const int half = co >> 7, co_l = co & 127;
    for (int s = t; s < 576; s += 256) {
        const int b = s / 72, r = s - b * 72;
        const int pos = r >> 3, cg = r & 7;
        bf16x8 v;
#pragma unroll
        for (int c = 0; c < 8; ++c) v[c] = accW[b * 576 + (cg * 8 + c) * 9 + pos];
        size_t o = (((((size_t)b * 9 + pos) * 4 + chunk) * 2 + half) * 8 + cg) * 128 + co_l;
        *(bf16x8*)(aggw + o * 8) = v;
    }
}

// ---------------------------------------------------------------------------
// Kernel 3: implicit-GEMM conv + bias + residual.  (v5b — v5 with W-DMA fix)
// grid = 256: bid = ytile*8 + b  (bid%8 == b -> per-sample 1.2MB aggw slice
// pinned to one XCD's L2).
// block = 256 (4 waves): tile = 256co x (2 rows x 64 cols).
// 64 MFMAs/wave/tap; W+X double-buffered in LDS (130KB, 1 block/CU).
// Schedule per tap: [issue next-W DMA (+next-X at chunk edge) -> 64 MFMA ->
// vmcnt(0) -> barrier]. ONE barrier/tap.
//
// v5 BUG FIXED: global_load_lds covers 64 lanes x 16B = 512 bf16 elems per
// instruction; v5 strided W pieces by 1024 elems (half of Ws never written).
// Now: wave stages a contiguous 4096-elem quarter as 8 DMAs x 512 elems.
// ---------------------------------------------------------------------------
__global__ __launch_bounds__(256, 1) void conv_kernel(
    const bf16* __restrict__ xt, const bf16* __restrict__ aggw,
    const float* __restrict__ aggb, const float* __restrict__ xin,
    float* __restrict__ out) {
    const int bid = blockIdx.x;
    const int b = bid & 7, ytile = bid >> 3;
    const int tid = threadIdx.x;
    const int wave = tid >> 6, lane = tid & 63;
    const int wm = wave & 1, wn = wave >> 1;
    const int lane15 = lane & 15, quad = lane >> 4;

    __shared__ __align__(16) bf16 Ws[2][16384];        // [buf][half|cg|co_l|c8] 64 KB
    __shared__ __align__(16) bf16 Xs[2][4][8][66][8];  // [buf][row][cg][col][c8] 67.6 KB

    f32x4 acc[8][4];
#pragma unroll
    for (int mt = 0; mt < 8; ++mt)
#pragma unroll
        for (int nt = 0; nt < 4; ++nt) acc[mt][nt] = f32x4{0.f, 0.f, 0.f, 0.f};

    // zero both X buffers once: halo cols 0/65 and out-of-image rows stay 0.
    {
        uint4 z; z.x = z.y = z.z = z.w = 0u;
        uint4* p = (uint4*)&Xs[0][0][0][0][0];
        for (int i = tid; i < 4224; i += 256) p[i] = z;
    }
    __syncthreads();  // zero-fill done before any DMA lands

    const int yrow = ytile * 2 - 1 + wave;          // wave w stages halo row w
    const bool rowok = (yrow >= 0) && (yrow < 64);
    const bf16* xsrc = xt + ((size_t)b * 64 + (rowok ? yrow : 0)) * 16384 + (size_t)lane * 8;
    bf16* xdst0 = &Xs[0][wave][0][1][0];            // +cg*528 per cg
    bf16* xdst1 = &Xs[1][wave][0][1][0];

    // W staging: slab(b,pos,chunk) = aggw + ((b*9+pos)*4+chunk)*16384 elems,
    // contiguous [half][cg][co_l][c8]. Wave stages its 4096-elem quarter as
    // 8 DMAs x 512 elems (64 lanes x 8 bf16 each).
    const bf16* wsrcw = aggw + (size_t)b * 589824 + (size_t)wave * 4096 + (size_t)lane * 8;
    bf16* wdstw0 = &Ws[0][0] + wave * 4096;
    bf16* wdstw1 = &Ws[1][0] + wave * 4096;

    // prologue: stage X chunk0 -> Xs[0], W(pos0,chunk0) -> Ws[0]
    if (rowok) {
#pragma unroll
        for (int cg = 0; cg < 8; ++cg)
            gload_lds16(xsrc + cg * 512, xdst0 + cg * 528);
    }
#pragma unroll
    for (int i = 0; i < 8; ++i)
        gload_lds16(wsrcw + i * 512, wdstw0 + i * 512);
    asm volatile("s_waitcnt vmcnt(0)" ::: "memory");
    __builtin_amdgcn_s_barrier();

    for (int chunk = 0; chunk < 4; ++chunk) {
        const bf16* xbase = (chunk & 1) ? &Xs[1][0][0][0][0] : &Xs[0][0][0][0][0];
        for (int pos = 0; pos < 9; ++pos) {
            const int t = chunk * 9 + pos;
            const bf16* wcur = (t & 1) ? &Ws[1][0] : &Ws[0][0];
            bf16* wnxt = (t & 1) ? wdstw0 : wdstw1;
            // ---- issue next tap's W stage into the idle buffer ----
            if (t < 35) {
                int npos = pos + 1, nchunk = chunk;
                if (npos == 9) { npos = 0; nchunk = chunk + 1; }
                const bf16* s0 = wsrcw + (size_t)(npos * 4 + nchunk) * 16384;
#pragma unroll
                for (int i = 0; i < 8; ++i)
                    gload_lds16(s0 + i * 512, wnxt + i * 512);
            }
            // ---- at chunk edge: issue next chunk's X stage (other buffer) --
            if (pos == 8 && chunk < 3 && rowok) {
                const bf16* s0 = xsrc + (size_t)(chunk + 1) * 4096;
                bf16* xd = (chunk & 1) ? xdst0 : xdst1;  // (chunk+1)&1
#pragma unroll
                for (int cg = 0; cg < 8; ++cg)
                    gload_lds16(s0 + cg * 512, xd + cg * 528);
            }
            // ---- compute tap: 64 MFMAs (covers the DMA latency) ----
            const int kh = (pos >= 6) ? 2 : (pos >= 3) ? 1 : 0;
            const int kw = pos - kh * 3;
            const int xr = wn + kh;
            const bf16* xrow = xbase + xr * 4224;
#pragma unroll
            for (int s_ = 0; s_ < 2; ++s_) {
                const int cg = s_ * 4 + quad;
                bf16x8 afr[8], bfr[4];
#pragma unroll
                for (int mt = 0; mt < 8; ++mt)
                    afr[mt] = *(const bf16x8*)(wcur + wm * 8192 + cg * 1024
                                               + (mt * 16 + lane15) * 8);
#pragma unroll
                for (int nt = 0; nt < 4; ++nt)
                    bfr[nt] = *(const bf16x8*)(xrow + cg * 528 + (kw + nt * 16 + lane15) * 8);
#pragma unroll
                for (int mt = 0; mt < 8; ++mt)
#pragma unroll
                    for (int nt = 0; nt < 4; ++nt)
                        acc[mt][nt] = __builtin_amdgcn_mfma_f32_16x16x32_bf16(
                            afr[mt], bfr[nt], acc[mt][nt], 0, 0, 0);
            }
            // ---- tap-end: drain this tap's DMAs (long covered), barrier ----
            if (t < 35) {
                asm volatile("s_waitcnt vmcnt(0)" ::: "memory");
                __builtin_amdgcn_s_barrier();
            }
        }
    }

    // epilogue: conv + agg_b + residual, fp32 out
    const int y = ytile * 2 + wn;
#pragma unroll
    for (int mt = 0; mt < 8; ++mt) {
#pragma unroll
        for (int r = 0; r < 4; ++r) {
            const int co = wm * 128 + mt * 16 + quad * 4 + r;
            const float bbv = aggb[b * 256 + co];
            const size_t rowbase = (((size_t)b * 256 + co) * 64 + y) * 64;
#pragma unroll
            for (int nt = 0; nt < 4; ++nt) {
                const size_t oidx = rowbase + nt * 16 + lane15;
                out[oidx] = acc[mt][nt][r] + bbv + xin[oidx];
            }
        }
    }
}

// ---------------------------------------------------------------------------
extern "C" void kernel_launch(void* const* d_in, const int* in_sizes, int n_in,
                              void* d_out, int out_size, void* d_ws, size_t ws_size,
                              hipStream_t stream) {
    const float* x    = (const float*)d_in[0];  // [8,256,64,64]
    const float* sk   = (const float*)d_in[1];  // [8,1,56,56]
    const float* wgt  = (const float*)d_in[2];  // [16,256,256,3,3]
    const float* bias = (const float*)d_in[3];  // [16,256]
    const float* w1   = (const float*)d_in[4];  // [196,784]
    const float* w2   = (const float*)d_in[5];  // [16,196]
    float* out = (float*)d_out;

    char* ws = (char*)d_ws;
    float* att  = (float*)(ws + 0);                      // 512 B
    float* aggb = (float*)(ws + 1024);                   // 8 KB
    bf16*  aggw = (bf16*)(ws + 16384);                   // 9,437,184 B
    bf16*  xt   = (bf16*)(ws + 16384 + 9437184);         // 16,777,216 B

    attn_kernel<<<8, 1024, 0, stream>>>(sk, w1, w2, att);
    aggt_kernel<<<1536, 256, 0, stream>>>(wgt, bias, att, aggw, aggb, x, xt);
    conv_kernel<<<256, 256, 0, stream>>>(xt, aggw, aggb, x, out);
}

// Round 6
// 178.761 us; speedup vs baseline: 1.1644x; 1.0669x over previous
//
#include <hip/hip_runtime.h>
#include <stdint.h>
#include <stddef.h>

typedef __bf16 bf16;
typedef __bf16 bf16x8 __attribute__((ext_vector_type(8)));
typedef __bf16 bf16x4 __attribute__((ext_vector_type(4)));
typedef __bf16 bf16x2 __attribute__((ext_vector_type(2)));
typedef float f32x4 __attribute__((ext_vector_type(4)));

static_assert(sizeof(bf16x8) == 16, "bf16x8 must be 16B");

__device__ __forceinline__ void gload_lds16(const void* g, void* l) {
    __builtin_amdgcn_global_load_lds(
        (const __attribute__((address_space(1))) uint32_t*)g,
        (__attribute__((address_space(3))) uint32_t*)l, 16, 0, 0);
}

// ---------------------------------------------------------------------------
// Kernel 1: attention  (pool 56x56 -> 28x28, MLP 784->196->16, softmax/T)
// grid = 8, block = 1024.  Coalesced w1 GEMV: 16 lanes per output row.
// ---------------------------------------------------------------------------
__global__ __launch_bounds__(1024) void attn_kernel(const float* __restrict__ sk,
                                                    const float* __restrict__ w1,
                                                    const float* __restrict__ w2,
                                                    float* __restrict__ att) {
    const int b = blockIdx.x, t = threadIdx.x;
    __shared__ float pooled[784];
    __shared__ float hdn[196];
    __shared__ float logits[16];
    const float* skb = sk + (size_t)b * 3136;
    if (t < 784) {
        int oy = t / 28, ox = t % 28;
        const float* p = skb + (oy * 2) * 56 + ox * 2;
        pooled[t] = 0.25f * (p[0] + p[1] + p[56] + p[57]);
    }
    __syncthreads();
    const int q = t & 15, jg = t >> 4;  // 64 groups of 16 lanes
#pragma unroll
    for (int rep = 0; rep < 4; ++rep) {
        const int j = rep * 64 + jg;
        float s = 0.f;
        if (j < 196) {
            const float* wr = w1 + (size_t)j * 784 + q;
#pragma unroll 7
            for (int i = 0; i < 49; ++i) s += pooled[q + i * 16] * wr[i * 16];
        }
#pragma unroll
        for (int off = 8; off; off >>= 1) s += __shfl_xor(s, off, 16);
        if (j < 196 && q == 0) hdn[j] = s > 0.f ? s : 0.f;
    }
    __syncthreads();
    if (t < 256) {
        const int jj = t >> 4, qq = t & 15;
        float s = 0.f;
#pragma unroll
        for (int i = 0; i < 13; ++i) {
            const int idx = qq + i * 16;
            if (idx < 196) s += hdn[idx] * w2[jj * 196 + idx];
        }
#pragma unroll
        for (int off = 8; off; off >>= 1) s += __shfl_xor(s, off, 16);
        if (qq == 0) logits[jj] = s * (1.0f / 30.0f);
    }
    __syncthreads();
    if (t == 0) {
        float m = logits[0];
        for (int k = 1; k < 16; ++k) m = fmaxf(m, logits[k]);
        float e16[16], sum = 0.f;
        for (int k = 0; k < 16; ++k) { e16[k] = expf(logits[k] - m); sum += e16[k]; }
        float inv = 1.f / sum;
        for (int k = 0; k < 16; ++k) att[b * 16 + k] = e16[k] * inv;
    }
}

// ---------------------------------------------------------------------------
// Kernel 2 (fused): agg v6 (blocks 0..127) + x transpose (blocks 128..639).
//
// agg v6: block = (chunk(4), cog(32)) owns 8 consecutive co. Produces, per
// (b,pos,cg), a CONTIGUOUS 128B piece [co_l 8][c8 8] of aggw -> full-line
// HBM writes (old kernel: isolated 16B pieces at 2KB stride, every 64B line
// split across 4 workgroups on different XCDs -> HBM RMW, ~4x write cost).
// Reads: float2 tasks, 512B-contiguous runs per wave, k-strided. Numerics
// identical (fp32 accumulate over 16 k, then bf16 round).
// agg_w2 layout: [b][pos][chunk(4)][half(2)][cg(8)][co_l(128)][c8(8)]  bf16
// ---------------------------------------------------------------------------
__global__ __launch_bounds__(256) void aggt_kernel(
    const float* __restrict__ weight,
    const float* __restrict__ bias,
    const float* __restrict__ att,
    bf16* __restrict__ aggw,
    float* __restrict__ aggb,
    const float* __restrict__ x,
    bf16* __restrict__ xt) {
    __shared__ __align__(16) char smem[73984];
    const int t = threadIdx.x;

    if (blockIdx.x >= 128) {
        // ---- transpose block: x[b][ci][y][x] fp32 -> xt bf16 ----
        const int bid = blockIdx.x - 128;
        const int b = bid >> 6, y = bid & 63;
        bf16* T = (bf16*)smem;  // [ci(256)][x(64)]
        const float* src = x + (size_t)b * 256 * 4096 + (size_t)y * 64;
        for (int i = 0; i < 16; ++i) {
            int v = t + 256 * i;              // 4096 float4 chunks
            int ci = v >> 4, x4 = (v & 15) * 4;
            float4 f = *(const float4*)(src + (size_t)ci * 4096 + x4);
            bf16* d = &T[ci * 64 + x4];
            d[0] = (bf16)f.x; d[1] = (bf16)f.y; d[2] = (bf16)f.z; d[3] = (bf16)f.w;
        }
        __syncthreads();
        bf16* dstb = xt + (size_t)bid * 16384;
        for (int i = 0; i < 8; ++i) {
            int c2 = t + 256 * i;             // 2048 16B chunks: [cg][x]
            int cg = c2 >> 6, xx = c2 & 63;
            bf16x8 v;
#pragma unroll
            for (int c = 0; c < 8; ++c) v[c] = T[(cg * 8 + c) * 64 + xx];
            *(bf16x8*)(dstb + (size_t)c2 * 8) = v;
        }
        return;
    }

    // ---- agg block: chunk = bid>>5, cog = bid&31; co = cog*8 + co_i ----
    const int chunk = blockIdx.x >> 5, cog = blockIdx.x & 31;
    const int half = cog >> 4;
    bf16* accW = (bf16*)smem;  // [co_i(8)][b(8)][e(stride 578)]

    if (chunk == 0 && t < 64) {
        const int b = t >> 3, co = cog * 8 + (t & 7);
        float s = 0.f;
        for (int k = 0; k < 16; ++k) s += att[b * 16 + k] * bias[k * 256 + co];
        aggb[b * 256 + co] = s;
    }

    // 2304 float2-tasks: id -> co_i = id/288, e2 = id%288 (elems 2e2,2e2+1)
#pragma unroll
    for (int r = 0; r < 9; ++r) {
        const int id = t + 256 * r;
        const int co_i = id / 288, e2 = id - co_i * 288;
        const int co = cog * 8 + co_i;
        const float* wbase = weight + (size_t)co * 2304 + (size_t)chunk * 576 + 2 * e2;
        float2 wv[16];
#pragma unroll
        for (int k = 0; k < 16; ++k)
            wv[k] = *(const float2*)(wbase + (size_t)k * 589824);
        float a[8][2];
#pragma unroll
        for (int b = 0; b < 8; ++b) { a[b][0] = 0.f; a[b][1] = 0.f; }
#pragma unroll
        for (int k = 0; k < 16; ++k) {
#pragma unroll
            for (int b = 0; b < 8; ++b) {
                const float av = att[b * 16 + k];  // uniform -> scalar load
                a[b][0] += av * wv[k].x;
                a[b][1] += av * wv[k].y;
            }
        }
#pragma unroll
        for (int b = 0; b < 8; ++b) {
            bf16x2 v; v[0] = (bf16)a[b][0]; v[1] = (bf16)a[b][1];
            *(bf16x2*)&accW[(co_i * 8 + b) * 578 + 2 * e2] = v;
        }
    }
    __syncthreads();

    // write-out: 4608 16B stores; piece (b,pos,cg) = contiguous 128B of aggw
    const int cogl = cog & 15;
#pragma unroll
    for (int i = 0; i < 18; ++i) {
        const int s = t + 256 * i;
        const int piece = s >> 3, sub = s & 7;
        const int b = piece / 72, r = piece - b * 72;
        const int pos = r >> 3, cg = r & 7;
        bf16x8 v;
#pragma unroll
        for (int c = 0; c < 8; ++c)
            v[c] = accW[(sub * 8 + b) * 578 + (cg * 8 + c) * 9 + pos];
        const size_t G = ((((size_t)b * 9 + pos) * 4 + chunk) * 2 + half) * 8 + cg;
        *(bf16x8*)(aggw + G * 1024 + cogl * 64 + sub * 8) = v;
    }
}

// ---------------------------------------------------------------------------
// Kernel 3: implicit-GEMM conv + bias + residual.  (v1 structure + XCD swizzle)
// grid = 512: bid = ytile*16 + (b*2+half)  ->  bid%8 fixed per (b,half)-ish:
// the 32 blocks sharing one 590KB aggw slice land on one XCD's L2 (v4-measured
// FETCH 69.5 -> 37.5 MB). Inner loop byte-identical to the 50.7us v1: 2
// blocks/CU gives cross-block overlap of the per-tap stage-drain.
// ---------------------------------------------------------------------------
__global__ __launch_bounds__(256, 2) void conv_kernel(
    const bf16* __restrict__ xt, const bf16* __restrict__ aggw,
    const float* __restrict__ aggb, const float* __restrict__ xin,
    float* __restrict__ out) {
    const int bid = blockIdx.x;
    const int slice = bid & 15, ytile = bid >> 4;
    const int b = slice >> 1, half = slice & 1;
    const int tid = threadIdx.x;
    const int wave = tid >> 6, lane = tid & 63;
    const int wm = wave & 1, wn = wave >> 1;
    const int lane15 = lane & 15, quad = lane >> 4;

    __shared__ __align__(16) bf16 Xs[4][8][66][8];  // [row][cg][col(padded)][c8]
    __shared__ __align__(16) bf16 Ws[8][128][8];    // [cg][co_l][c8]

    f32x4 acc[4][4];
#pragma unroll
    for (int mt = 0; mt < 4; ++mt)
#pragma unroll
        for (int nt = 0; nt < 4; ++nt) acc[mt][nt] = f32x4{0.f, 0.f, 0.f, 0.f};

    // zero the whole X tile once: halo cols 0/65 and out-of-image rows stay 0.
    {
        uint4 z; z.x = z.y = z.z = z.w = 0u;
        uint4* p = (uint4*)&Xs[0][0][0][0];
        for (int i = tid; i < 2112; i += 256) p[i] = z;
    }

    const int yrow = ytile * 2 - 1 + wave;          // wave w stages halo row w
    const bool rowok = (yrow >= 0) && (yrow < 64);
    const bf16* xsrc = xt + ((size_t)b * 64 + (rowok ? yrow : 0)) * 16384 + (size_t)lane * 8;
    bf16* xdstbase = &Xs[wave][0][1][0];            // +cg*528 per cg

    for (int chunk = 0; chunk < 4; ++chunk) {
        __syncthreads();                            // prev compute done (and zero-fill)
        if (rowok) {
            const bf16* s0 = xsrc + (size_t)chunk * 4096;
#pragma unroll
            for (int cg = 0; cg < 8; ++cg)
                gload_lds16(s0 + cg * 512, xdstbase + cg * 528);
        }
        const bf16* wchunkbase = aggw + (((size_t)b * 36 + chunk) * 2 + half) * 8192;
        for (int pos = 0; pos < 9; ++pos) {
            if (pos) __syncthreads();               // prev tap done reading Ws
            const bf16* wsrc = wchunkbase + (size_t)pos * 65536 + wave * 2048 + (size_t)lane * 8;
            bf16* wdst = ((bf16*)Ws) + wave * 2048;
#pragma unroll
            for (int i = 0; i < 4; ++i)
                gload_lds16(wsrc + i * 512, wdst + i * 512);
            __syncthreads();                        // drains vmcnt (global_load_lds)
            const int kh = pos / 3, kw = pos - kh * 3;
            const int xr = wn + kh;
#pragma unroll
            for (int s = 0; s < 2; ++s) {
                const int cg = s * 4 + quad;
                bf16x8 afr[4], bfr[4];
#pragma unroll
                for (int mt = 0; mt < 4; ++mt)
                    afr[mt] = *(const bf16x8*)&Ws[cg][wm * 64 + mt * 16 + lane15][0];
#pragma unroll
                for (int nt = 0; nt < 4; ++nt)
                    bfr[nt] = *(const bf16x8*)&Xs[xr][cg][kw + nt * 16 + lane15][0];
#pragma unroll
                for (int mt = 0; mt < 4; ++mt)
#pragma unroll
                    for (int nt = 0; nt < 4; ++nt)
                        acc[mt][nt] = __builtin_amdgcn_mfma_f32_16x16x32_bf16(
                            afr[mt], bfr[nt], acc[mt][nt], 0, 0, 0);
            }
        }
    }

    // epilogue: conv + agg_b + residual, fp32 out
    const int y = ytile * 2 + wn;
#pragma unroll
    for (int mt = 0; mt < 4; ++mt) {
#pragma unroll
        for (int r = 0; r < 4; ++r) {
            const int co = half * 128 + wm * 64 + mt * 16 + quad * 4 + r;
            const float bbv = aggb[b * 256 + co];
            const size_t rowbase = (((size_t)b * 256 + co) * 64 + y) * 64;
#pragma unroll
            for (int nt = 0; nt < 4; ++nt) {
                const size_t oidx = rowbase + nt * 16 + lane15;
                out[oidx] = acc[mt][nt][r] + bbv + xin[oidx];
            }
        }
    }
}

// ---------------------------------------------------------------------------
extern "C" void kernel_launch(void* const* d_in, const int* in_sizes, int n_in,
                              void* d_out, int out_size, void* d_ws, size_t ws_size,
                              hipStream_t stream) {
    const float* x    = (const float*)d_in[0];  // [8,256,64,64]
    const float* sk   = (const float*)d_in[1];  // [8,1,56,56]
    const float* wgt  = (const float*)d_in[2];  // [16,256,256,3,3]
    const float* bias = (const float*)d_in[3];  // [16,256]
    const float* w1   = (const float*)d_in[4];  // [196,784]
    const float* w2   = (const float*)d_in[5];  // [16,196]
    float* out = (float*)d_out;

    char* ws = (char*)d_ws;
    float* att  = (float*)(ws + 0);                      // 512 B
    float* aggb = (float*)(ws + 1024);                   // 8 KB
    bf16*  aggw = (bf16*)(ws + 16384);                   // 9,437,184 B
    bf16*  xt   = (bf16*)(ws + 16384 + 9437184);         // 16,777,216 B

    attn_kernel<<<8, 1024, 0, stream>>>(sk, w1, w2, att);
    aggt_kernel<<<640, 256, 0, stream>>>(wgt, bias, att, aggw, aggb, x, xt);
    conv_kernel<<<512, 256, 0, stream>>>(xt, aggw, aggb, x, out);
}